// Round 3
// baseline (57.280 us; speedup 1.0000x reference)
//
#include <hip/hip_runtime.h>

// Problem constants (from reference)
#define BB 2
#define NN 32768
#define SS 1024
#define CSRC 35
#define KK 32
#define R2 1.0f
#define COUT 39     // 3 (xyz-kp) + 1 (intensity) + 35 (source)
#define CHUNKS 16   // points per scan iteration = CHUNKS*256 = 4096

// ---- Pre-pass: pack {x, y, z, (x*x+y*y)+z*z}, fully coalesced via LDS ----
// One block = 256 consecutive points = 256*35 floats = 35840 B (16B-aligned tile).
__global__ __launch_bounds__(256) void pack_kernel(
    const float* __restrict__ src,   // B*N*35
    float4* __restrict__ pk)         // B*N
{
    __shared__ float buf[256 * CSRC];          // 35840 B
    const int blk = blockIdx.x;                // 0 .. B*N/256 - 1
    const float4* s4 = (const float4*)(src + (size_t)blk * 256 * CSRC);
    float4* b4 = (float4*)buf;
    #pragma unroll
    for (int t = threadIdx.x; t < 256 * CSRC / 4; t += 256) b4[t] = s4[t];
    __syncthreads();
    const int t = threadIdx.x;
    const float x = buf[t * CSRC + 0];
    const float y = buf[t * CSRC + 1];
    const float z = buf[t * CSRC + 2];
    // EXACT reference association: (x*x + y*y) + z*z, no FMA contraction
    const float xq = __fadd_rn(__fadd_rn(__fmul_rn(x, x), __fmul_rn(y, y)),
                               __fmul_rn(z, z));
    pk[(size_t)blk * 256 + t] = make_float4(x, y, z, xq);
}

// ---- Main: one 256-thread block (4 waves) per keypoint, 4096 pts/iter ----
__global__ __launch_bounds__(256, 4) void dfe_kernel(
    const float* __restrict__ src,    // B*N*35
    const float* __restrict__ inten,  // B*N
    const float* __restrict__ kpt,    // B*S*4
    const float4* __restrict__ pk,    // B*N packed {x,y,z,xq}
    float* __restrict__ out)          // B*S*K*39
{
    const int tid  = threadIdx.x;          // 0..255
    const int lane = tid & 63;
    const int w    = tid >> 6;             // wave 0..3
    const int kp_id = blockIdx.x;          // 0 .. B*S-1
    const int b     = kp_id >> 10;         // S = 1024

    __shared__ __attribute__((aligned(16))) int cnt[CHUNKS][4];  // [chunk][wave]
    __shared__ int sidx[KK];

    const float* kp = kpt + (size_t)kp_id * 4;
    const float kx = kp[0], ky = kp[1], kz = kp[2];
    const float kq = __fadd_rn(__fadd_rn(__fmul_rn(kx, kx), __fmul_rn(ky, ky)),
                               __fmul_rn(kz, kz));

    const float*  sb = src   + (size_t)b * NN * CSRC;
    const float*  ib = inten + (size_t)b * NN;
    const float4* pb = pk    + (size_t)b * NN;

    // ---- Phase A: ordered scan, 4096 points / iteration ----
    int count = 0;
    for (int base = 0; base < NN; base += CHUNKS * 256) {
        unsigned long long m[CHUNKS];
        #pragma unroll
        for (int c = 0; c < CHUNKS; ++c) {
            const int i = base + c * 256 + tid;
            const float4 p = pb[i];
            const float dot = __fadd_rn(__fadd_rn(__fmul_rn(kx, p.x), __fmul_rn(ky, p.y)),
                                        __fmul_rn(kz, p.z));
            // sq = (kq + xq) - 2.0*dot  -- exact reference association
            const float sq = __fsub_rn(__fadd_rn(kq, p.w), __fmul_rn(2.0f, dot));
            const bool in = !(sq > R2);
            m[c] = __ballot(in);
            if (lane == 0) cnt[c][w] = __popcll(m[c]);
        }
        __syncthreads();
        // ordered slot = count + hits in earlier chunks + earlier waves (same
        // chunk) + earlier lanes (same wave)
        int chunk_base = count;
        #pragma unroll
        for (int c = 0; c < CHUNKS; ++c) {
            const int4 cc = *(const int4*)cnt[c];   // counts of waves 0..3
            if ((m[c] >> lane) & 1ull) {
                int off = chunk_base;
                if (w > 0) off += cc.x;
                if (w > 1) off += cc.y;
                if (w > 2) off += cc.z;
                off += __popcll(m[c] & ((1ull << lane) - 1ull));
                if (off < KK) sidx[off] = base + c * 256 + tid;
            }
            chunk_base += cc.x + cc.y + cc.z + cc.w;
        }
        count = chunk_base;                         // uniform across block
        __syncthreads();                            // sidx/cnt settled
        if (count >= KK) break;
    }

    // ---- Pad with first index (count >= 1: keypoint s == source row s) ----
    const int cclamp = count < KK ? count : KK;
    const int first = sidx[0];
    if (tid >= cclamp && tid < KK) sidx[tid] = first;
    __syncthreads();

    // ---- Phase B: gather + write 32*39 = 1248 floats with 256 threads ----
    float* ob = out + (size_t)kp_id * (KK * COUT);
    for (int t = tid; t < KK * COUT; t += 256) {
        const int k = t / COUT;
        const int j = t - k * COUT;
        const int i = sidx[k];
        float v;
        if (j < 3) {
            const float kc = (j == 0) ? kx : ((j == 1) ? ky : kz);
            v = __fsub_rn(sb[(size_t)i * CSRC + j], kc);
        } else if (j == 3) {
            v = ib[i];
        } else {
            v = sb[(size_t)i * CSRC + (j - 4)];
        }
        ob[t] = v;
    }
}

extern "C" void kernel_launch(void* const* d_in, const int* in_sizes, int n_in,
                              void* d_out, int out_size, void* d_ws, size_t ws_size,
                              hipStream_t stream) {
    const float* src   = (const float*)d_in[0];  // (B, N, 35)
    const float* inten = (const float*)d_in[1];  // (B, N, 1)
    const float* kpt   = (const float*)d_in[2];  // (B, S, 4)
    float* out = (float*)d_out;                  // (B, S, K, 39)
    float4* pk = (float4*)d_ws;                  // B*N*16 B = 1 MiB

    pack_kernel<<<BB * NN / 256, 256, 0, stream>>>(src, pk);
    dfe_kernel<<<BB * SS, 256, 0, stream>>>(src, inten, kpt, pk, out);
}

// Round 4
// 46.192 us; speedup vs baseline: 1.2400x; 1.2400x over previous
//
#include <hip/hip_runtime.h>

// Problem constants (from reference)
#define BB 2
#define NN 32768
#define SS 1024
#define CSRC 35
#define KK 32
#define R2 1.0f
#define COUT 39   // 3 (xyz-kp) + 1 (intensity) + 35 (source)
#define CH 32     // chunks per scan iteration; points/iter = CH*64 = 2048

// ---- Pre-pass: pack {x, y, z, (x*x+y*y)+z*z}, fully coalesced via LDS ----
__global__ __launch_bounds__(256) void pack_kernel(
    const float* __restrict__ src,   // B*N*35
    float4* __restrict__ pk)         // B*N
{
    __shared__ float buf[256 * CSRC];          // 35840 B
    const int blk = blockIdx.x;                // 0 .. B*N/256 - 1
    const float4* s4 = (const float4*)(src + (size_t)blk * 256 * CSRC);
    float4* b4 = (float4*)buf;
    #pragma unroll
    for (int t = threadIdx.x; t < 256 * CSRC / 4; t += 256) b4[t] = s4[t];
    __syncthreads();
    const int t = threadIdx.x;
    const float x = buf[t * CSRC + 0];
    const float y = buf[t * CSRC + 1];
    const float z = buf[t * CSRC + 2];
    // EXACT reference association: (x*x + y*y) + z*z, no FMA contraction
    const float xq = __fadd_rn(__fadd_rn(__fmul_rn(x, x), __fmul_rn(y, y)),
                               __fmul_rn(z, z));
    pk[(size_t)blk * 256 + t] = make_float4(x, y, z, xq);
}

// ---- Main: one WAVE per keypoint (8 waves / 512-thread block), no barriers.
//      Per iteration: 32 back-to-back float4 loads (one latency), then
//      wave-local ordered ballot-compaction into per-wave LDS. ----
__global__ __launch_bounds__(512, 2) void dfe_kernel(
    const float* __restrict__ src,    // B*N*35
    const float* __restrict__ inten,  // B*N
    const float* __restrict__ kpt,    // B*S*4
    const float4* __restrict__ pk,    // B*N packed {x,y,z,xq}
    float* __restrict__ out)          // B*S*K*39
{
    const int lane = threadIdx.x & 63;
    const int w    = threadIdx.x >> 6;              // wave 0..7
    const int kp_id = blockIdx.x * 8 + w;           // 0 .. B*S-1
    const int b     = kp_id >> 10;                  // S = 1024

    __shared__ int sidx[8][KK];                     // per-wave index lists

    const float* kp = kpt + (size_t)kp_id * 4;
    const float kx = kp[0], ky = kp[1], kz = kp[2];
    const float kq = __fadd_rn(__fadd_rn(__fmul_rn(kx, kx), __fmul_rn(ky, ky)),
                               __fmul_rn(kz, kz));

    const float*  sb = src   + (size_t)b * NN * CSRC;
    const float*  ib = inten + (size_t)b * NN;
    const float4* pb = pk    + (size_t)b * NN;

    // ---- Phase A: ordered scan, 2048 points / iteration per wave ----
    int count = 0;
    for (int base = 0; base < NN && count < KK; base += CH * 64) {
        float4 p[CH];
        // pure load batch -> all 32 loads in flight, ~one memory latency
        #pragma unroll
        for (int c = 0; c < CH; ++c) p[c] = pb[base + c * 64 + lane];
        // wave-local ordered compaction, no cross-wave traffic
        #pragma unroll
        for (int c = 0; c < CH; ++c) {
            const float dot = __fadd_rn(
                __fadd_rn(__fmul_rn(kx, p[c].x), __fmul_rn(ky, p[c].y)),
                __fmul_rn(kz, p[c].z));
            // sq = (kq + xq) - 2.0*dot  -- exact reference association
            const float sq = __fsub_rn(__fadd_rn(kq, p[c].w),
                                       __fmul_rn(2.0f, dot));
            const bool in = !(sq > R2);
            const unsigned long long m = __ballot(in);
            if (in) {
                const int off = count + __popcll(m & ((1ull << lane) - 1ull));
                if (off < KK) sidx[w][off] = base + c * 64 + lane;
            }
            count += __popcll(m);
        }
    }

    // ---- Pad with first index (count >= 1: keypoint s == source row s) ----
    const int cclamp = count < KK ? count : KK;
    const int first = sidx[w][0];
    if (lane >= cclamp && lane < KK) sidx[w][lane] = first;

    // ---- Phase B: gather + write 32*39 = 1248 floats with 64 lanes ----
    float* ob = out + (size_t)kp_id * (KK * COUT);
    for (int t = lane; t < KK * COUT; t += 64) {
        const int k = t / COUT;
        const int j = t - k * COUT;
        const int i = sidx[w][k];
        float v;
        if (j < 3) {
            const float kc = (j == 0) ? kx : ((j == 1) ? ky : kz);
            v = __fsub_rn(sb[(size_t)i * CSRC + j], kc);
        } else if (j == 3) {
            v = ib[i];
        } else {
            v = sb[(size_t)i * CSRC + (j - 4)];
        }
        ob[t] = v;
    }
}

extern "C" void kernel_launch(void* const* d_in, const int* in_sizes, int n_in,
                              void* d_out, int out_size, void* d_ws, size_t ws_size,
                              hipStream_t stream) {
    const float* src   = (const float*)d_in[0];  // (B, N, 35)
    const float* inten = (const float*)d_in[1];  // (B, N, 1)
    const float* kpt   = (const float*)d_in[2];  // (B, S, 4)
    float* out = (float*)d_out;                  // (B, S, K, 39)
    float4* pk = (float4*)d_ws;                  // B*N*16 B = 1 MiB

    pack_kernel<<<BB * NN / 256, 256, 0, stream>>>(src, pk);
    dfe_kernel<<<BB * SS / 8, 512, 0, stream>>>(src, inten, kpt, pk, out);
}

// Round 5
// 39.710 us; speedup vs baseline: 1.4425x; 1.1633x over previous
//
#include <hip/hip_runtime.h>

// Problem constants (from reference)
#define BB 2
#define NN 32768
#define SS 1024
#define CSRC 35
#define KK 32
#define R2 1.0f
#define COUT 39     // 3 (xyz-kp) + 1 (intensity) + 35 (source)
#define NKP (BB * SS)
#define SCAN0 2048  // fast-path prefix length

// ws layout:
//   [0, 1 MiB)        float4 pk[BB*NN]   packed {x,y,z,xq}
//   [1 MiB, +4)       int qcount
//   [1 MiB+64, ...)   int queue[NKP]

__device__ __forceinline__ float sq_ref(float kx, float ky, float kz, float kq,
                                        float4 p) {
    // EXACT reference association, no FMA contraction:
    // dot = (kx*x + ky*y) + kz*z ; sq = (kq + xq) - 2*dot
    const float dot = __fadd_rn(__fadd_rn(__fmul_rn(kx, p.x), __fmul_rn(ky, p.y)),
                                __fmul_rn(kz, p.z));
    return __fsub_rn(__fadd_rn(kq, p.w), __fmul_rn(2.0f, dot));
}

__device__ __forceinline__ void emit(int t0, int stride, const float* sb,
                                     const float* ib, const int* sidx_,
                                     float kx, float ky, float kz, float* ob) {
    for (int t = t0; t < KK * COUT; t += stride) {
        const int k = t / COUT;
        const int j = t - k * COUT;
        const int i = sidx_[k];
        float v;
        if (j < 3) {
            const float kc = (j == 0) ? kx : ((j == 1) ? ky : kz);
            v = __fsub_rn(sb[(size_t)i * CSRC + j], kc);
        } else if (j == 3) {
            v = ib[i];
        } else {
            v = sb[(size_t)i * CSRC + (j - 4)];
        }
        ob[t] = v;
    }
}

// ---- Pre-pass: pack {x,y,z,xq} coalesced via LDS; zero the tail queue ----
__global__ __launch_bounds__(256) void pack_kernel(
    const float* __restrict__ src, float4* __restrict__ pk, int* __restrict__ qc)
{
    if (blockIdx.x == 0 && threadIdx.x == 0) *qc = 0;
    __shared__ float buf[256 * CSRC];
    const int blk = blockIdx.x;
    const float4* s4 = (const float4*)(src + (size_t)blk * 256 * CSRC);
    float4* b4 = (float4*)buf;
    #pragma unroll
    for (int t = threadIdx.x; t < 256 * CSRC / 4; t += 256) b4[t] = s4[t];
    __syncthreads();
    const int t = threadIdx.x;
    const float x = buf[t * CSRC + 0];
    const float y = buf[t * CSRC + 1];
    const float z = buf[t * CSRC + 2];
    const float xq = __fadd_rn(__fadd_rn(__fmul_rn(x, x), __fmul_rn(y, y)),
                               __fmul_rn(z, z));
    pk[(size_t)blk * 256 + t] = make_float4(x, y, z, xq);
}

// ---- Fast path: one wave per keypoint, scan first SCAN0 points only ----
__global__ __launch_bounds__(512, 2) void dfe_fast(
    const float* __restrict__ src, const float* __restrict__ inten,
    const float* __restrict__ kpt, const float4* __restrict__ pk,
    float* __restrict__ out, int* __restrict__ qc, int* __restrict__ queue)
{
    const int lane = threadIdx.x & 63;
    const int wv   = threadIdx.x >> 6;          // 0..7
    const int kp_id = blockIdx.x * 8 + wv;
    const int b     = kp_id >> 10;

    __shared__ int sidx[8][KK];

    const float* kp = kpt + (size_t)kp_id * 4;
    const float kx = kp[0], ky = kp[1], kz = kp[2];
    const float kq = __fadd_rn(__fadd_rn(__fmul_rn(kx, kx), __fmul_rn(ky, ky)),
                               __fmul_rn(kz, kz));
    const float4* pb = pk + (size_t)b * NN;

    int count = 0;
    // half 1: points [0, 1024) — 16 loads batched in registers
    {
        float4 p[16];
        #pragma unroll
        for (int j = 0; j < 16; ++j) p[j] = pb[j * 64 + lane];
        #pragma unroll
        for (int j = 0; j < 16; ++j) {
            const bool in = !(sq_ref(kx, ky, kz, kq, p[j]) > R2);
            const unsigned long long m = __ballot(in);
            if (in) {
                const int off = count + __popcll(m & ((1ull << lane) - 1ull));
                if (off < KK) sidx[wv][off] = j * 64 + lane;
            }
            count += __popcll(m);
        }
    }
    if (count < KK) {  // half 2: points [1024, 2048)
        float4 p[16];
        #pragma unroll
        for (int j = 0; j < 16; ++j) p[j] = pb[1024 + j * 64 + lane];
        #pragma unroll
        for (int j = 0; j < 16; ++j) {
            const bool in = !(sq_ref(kx, ky, kz, kq, p[j]) > R2);
            const unsigned long long m = __ballot(in);
            if (in) {
                const int off = count + __popcll(m & ((1ull << lane) - 1ull));
                if (off < KK) sidx[wv][off] = 1024 + j * 64 + lane;
            }
            count += __popcll(m);
        }
    }

    if (count < KK) {   // defer to tail kernel
        if (lane == 0) {
            const int pos = atomicAdd(qc, 1);
            queue[pos] = kp_id;
        }
        return;
    }
    // count >= KK: all 32 slots filled with the global first-32 (prefix property)
    const float* sb = src   + (size_t)b * NN * CSRC;
    const float* ib = inten + (size_t)b * NN;
    emit(lane, 64, sb, ib, sidx[wv], kx, ky, kz,
         out + (size_t)kp_id * (KK * COUT));
}

// ---- Tail: one 512-thread block per queued keypoint, full-N parallel scan ----
__global__ __launch_bounds__(512, 2) void dfe_tail(
    const float* __restrict__ src, const float* __restrict__ inten,
    const float* __restrict__ kpt, const float4* __restrict__ pk,
    float* __restrict__ out, const int* __restrict__ qc,
    const int* __restrict__ queue)
{
    __shared__ int cnt[64][8];    // [chunk][wave]
    __shared__ int excl[512];     // exclusive prefix per (chunk,wave)
    __shared__ int wsum[8];
    __shared__ int sidx[KK];

    const int nt = *qc;
    const int t    = threadIdx.x;
    const int lane = t & 63;
    const int wv   = t >> 6;

    for (int q = blockIdx.x; q < nt; q += gridDim.x) {
        const int kp_id = queue[q];
        const int b     = kp_id >> 10;

        const float* kp = kpt + (size_t)kp_id * 4;
        const float kx = kp[0], ky = kp[1], kz = kp[2];
        const float kq = __fadd_rn(__fadd_rn(__fmul_rn(kx, kx), __fmul_rn(ky, ky)),
                                   __fmul_rn(kz, kz));
        const float4* pb = pk + (size_t)b * NN;

        // Phase 1: 64 chunks of 512 points; thread t tests point c*512+t.
        unsigned long long bits = 0;
        #pragma unroll
        for (int g = 0; g < 8; ++g) {
            float4 p[8];
            #pragma unroll
            for (int j = 0; j < 8; ++j) p[j] = pb[(g * 8 + j) * 512 + t];
            #pragma unroll
            for (int j = 0; j < 8; ++j) {
                const int c = g * 8 + j;
                const bool in = !(sq_ref(kx, ky, kz, kq, p[j]) > R2);
                const unsigned long long m = __ballot(in);
                if (in) bits |= (1ull << c);
                if (lane == 0) cnt[c][wv] = __popcll(m);
            }
        }
        __syncthreads();

        // Phase 2: block-wide exclusive scan over o = c*8 + w (thread t owns o=t)
        const int v = cnt[t >> 3][t & 7];
        int inc = v;
        #pragma unroll
        for (int d = 1; d < 64; d <<= 1) {
            const int u = __shfl_up(inc, d);
            if (lane >= d) inc += u;
        }
        if (lane == 63) wsum[wv] = inc;
        __syncthreads();
        int base = 0;
        for (int j = 0; j < 8; ++j) if (j < wv) base += wsum[j];
        excl[t] = base + inc - v;
        int tot = 0;
        #pragma unroll
        for (int j = 0; j < 8; ++j) tot += wsum[j];
        __syncthreads();

        // Phase 3: ordered scatter of the first KK hits
        for (int c = 0; c < 64; ++c) {
            if (excl[c * 8] >= KK) break;          // block-uniform early out
            const bool in = (bits >> c) & 1ull;
            const unsigned long long m = __ballot(in);
            if (in) {
                const int off = excl[c * 8 + wv] +
                                __popcll(m & ((1ull << lane) - 1ull));
                if (off < KK) sidx[off] = c * 512 + t;
            }
        }
        __syncthreads();

        // Pad with first hit (>=1 guaranteed: keypoint row itself)
        const int cc = tot < KK ? tot : KK;
        const int first = sidx[0];
        if (t >= cc && t < KK) sidx[t] = first;
        __syncthreads();

        const float* sb = src   + (size_t)b * NN * CSRC;
        const float* ib = inten + (size_t)b * NN;
        emit(t, 512, sb, ib, sidx, kx, ky, kz,
             out + (size_t)kp_id * (KK * COUT));
        __syncthreads();   // protect LDS before next queue entry
    }
}

extern "C" void kernel_launch(void* const* d_in, const int* in_sizes, int n_in,
                              void* d_out, int out_size, void* d_ws, size_t ws_size,
                              hipStream_t stream) {
    const float* src   = (const float*)d_in[0];  // (B, N, 35)
    const float* inten = (const float*)d_in[1];  // (B, N, 1)
    const float* kpt   = (const float*)d_in[2];  // (B, S, 4)
    float* out = (float*)d_out;                  // (B, S, K, 39)

    char* ws = (char*)d_ws;
    float4* pk   = (float4*)ws;                      // 1 MiB
    int* qc      = (int*)(ws + (1 << 20));
    int* queue   = (int*)(ws + (1 << 20) + 64);

    pack_kernel<<<BB * NN / 256, 256, 0, stream>>>(src, pk, qc);
    dfe_fast<<<NKP / 8, 512, 0, stream>>>(src, inten, kpt, pk, out, qc, queue);
    dfe_tail<<<512, 512, 0, stream>>>(src, inten, kpt, pk, out, qc, queue);
}

// Round 6
// 36.879 us; speedup vs baseline: 1.5532x; 1.0767x over previous
//
#include <hip/hip_runtime.h>

// Problem constants (from reference)
#define BB 2
#define NN 32768
#define SS 1024
#define CSRC 35
#define KK 32
#define R2 1.0f
#define COUT 39      // 3 (xyz-kp) + 1 (intensity) + 35 (source)
#define NKP (BB * SS)
#define CHPTS 2048   // points per scan chunk = 256 threads * 8

__device__ __forceinline__ float sq_ref(float kx, float ky, float kz, float kq,
                                        float4 p) {
    // EXACT reference association, no FMA contraction:
    // dot = (kx*x + ky*y) + kz*z ; sq = (kq + xq) - 2*dot
    const float dot = __fadd_rn(__fadd_rn(__fmul_rn(kx, p.x), __fmul_rn(ky, p.y)),
                                __fmul_rn(kz, p.z));
    return __fsub_rn(__fadd_rn(kq, p.w), __fmul_rn(2.0f, dot));
}

// ---- Pre-pass: pack {x,y,z,(x*x+y*y)+z*z} coalesced via LDS ----
__global__ __launch_bounds__(256) void pack_kernel(
    const float* __restrict__ src, float4* __restrict__ pk)
{
    __shared__ float buf[256 * CSRC];          // 35840 B
    const int blk = blockIdx.x;                // 0 .. B*N/256-1
    const float4* s4 = (const float4*)(src + (size_t)blk * 256 * CSRC);
    float4* b4 = (float4*)buf;
    #pragma unroll
    for (int t = threadIdx.x; t < 256 * CSRC / 4; t += 256) b4[t] = s4[t];
    __syncthreads();
    const int t = threadIdx.x;
    const float x = buf[t * CSRC + 0];
    const float y = buf[t * CSRC + 1];
    const float z = buf[t * CSRC + 2];
    const float xq = __fadd_rn(__fadd_rn(__fmul_rn(x, x), __fmul_rn(y, y)),
                               __fmul_rn(z, z));
    pk[(size_t)blk * 256 + t] = make_float4(x, y, z, xq);
}

// ---- Fused: one 256-thread block (4 waves) per keypoint.
//      Chunked scan (2048 pts/chunk) with block-parallel ordered compaction;
//      early exit once 32 hits found. ----
__global__ __launch_bounds__(256, 4) void dfe_fused(
    const float* __restrict__ src,    // B*N*35
    const float* __restrict__ inten,  // B*N
    const float* __restrict__ kpt,    // B*S*4
    const float4* __restrict__ pk,    // B*N packed {x,y,z,xq}
    float* __restrict__ out)          // B*S*K*39
{
    const int tid  = threadIdx.x;      // 0..255
    const int lane = tid & 63;
    const int wv   = tid >> 6;         // 0..3
    const int kp_id = blockIdx.x;      // 0 .. NKP-1
    const int b     = kp_id >> 10;     // S = 1024

    __shared__ __attribute__((aligned(16))) int cnt[8][4];  // [sub][wave]
    __shared__ int sidx[KK];

    const float* kp = kpt + (size_t)kp_id * 4;
    const float kx = kp[0], ky = kp[1], kz = kp[2];
    const float kq = __fadd_rn(__fadd_rn(__fmul_rn(kx, kx), __fmul_rn(ky, ky)),
                               __fmul_rn(kz, kz));
    const float4* pb = pk + (size_t)b * NN;

    int count = 0;
    for (int base = 0; base < NN; base += CHPTS) {
        // pure load batch: 8 independent float4 loads -> one memory latency
        float4 p[8];
        #pragma unroll
        for (int j = 0; j < 8; ++j) p[j] = pb[base + j * 256 + tid];

        unsigned long long m[8];
        #pragma unroll
        for (int j = 0; j < 8; ++j) {
            const bool in = !(sq_ref(kx, ky, kz, kq, p[j]) > R2);
            m[j] = __ballot(in);
            if (lane == 0) cnt[j][wv] = __popcll(m[j]);
        }
        __syncthreads();

        // ordered slot = count + hits in earlier subchunks + earlier waves
        //                (same sub) + earlier lanes (same wave)
        int cb = count;
        #pragma unroll
        for (int j = 0; j < 8; ++j) {
            const int4 cc = *(const int4*)cnt[j];
            if ((m[j] >> lane) & 1ull) {
                int off = cb;
                if (wv > 0) off += cc.x;
                if (wv > 1) off += cc.y;
                if (wv > 2) off += cc.z;
                off += __popcll(m[j] & ((1ull << lane) - 1ull));
                if (off < KK) sidx[off] = base + j * 256 + tid;
            }
            cb += cc.x + cc.y + cc.z + cc.w;
        }
        count = cb;                    // block-uniform
        __syncthreads();               // sidx/cnt settled before reuse
        if (count >= KK) break;        // uniform branch
    }

    // Pad with first hit (count >= 1: keypoint row s < 1024 is in chunk 0
    // and evaluates to sq == 0 exactly)
    const int cclamp = count < KK ? count : KK;
    const int first = sidx[0];
    if (tid >= cclamp && tid < KK) sidx[tid] = first;
    __syncthreads();

    // ---- Emit 32*39 = 1248 floats: batch all loads, then all stores ----
    const float* sb = src   + (size_t)b * NN * CSRC;
    const float* ib = inten + (size_t)b * NN;
    float* ob = out + (size_t)kp_id * (KK * COUT);

    float v[5];
    #pragma unroll
    for (int u = 0; u < 5; ++u) {
        const int t = tid + u * 256;
        if (t < KK * COUT) {
            const int k = t / COUT;
            const int j = t - k * COUT;
            const int i = sidx[k];
            if (j < 3) {
                const float kc = (j == 0) ? kx : ((j == 1) ? ky : kz);
                v[u] = __fsub_rn(sb[(size_t)i * CSRC + j], kc);
            } else if (j == 3) {
                v[u] = ib[i];
            } else {
                v[u] = sb[(size_t)i * CSRC + (j - 4)];
            }
        }
    }
    #pragma unroll
    for (int u = 0; u < 5; ++u) {
        const int t = tid + u * 256;
        if (t < KK * COUT) ob[t] = v[u];
    }
}

extern "C" void kernel_launch(void* const* d_in, const int* in_sizes, int n_in,
                              void* d_out, int out_size, void* d_ws, size_t ws_size,
                              hipStream_t stream) {
    const float* src   = (const float*)d_in[0];  // (B, N, 35)
    const float* inten = (const float*)d_in[1];  // (B, N, 1)
    const float* kpt   = (const float*)d_in[2];  // (B, S, 4)
    float* out = (float*)d_out;                  // (B, S, K, 39)
    float4* pk = (float4*)d_ws;                  // 1 MiB

    pack_kernel<<<BB * NN / 256, 256, 0, stream>>>(src, pk);
    dfe_fused<<<NKP, 256, 0, stream>>>(src, inten, kpt, pk, out);
}